// Round 8
// baseline (37.642 us; speedup 1.0000x reference)
//
#include <hip/hip_runtime.h>

typedef float f4 __attribute__((ext_vector_type(4)));
typedef float f2 __attribute__((ext_vector_type(2)));

#define PAD 68              // LDS row pitch (floats); 68%32=4 spreads banks
#define NPART 512           // gram blocks = partial count (2 blocks/CU)
#define PART_STRIDE 12288   // 3 * 64*64 floats per block partial
#define NBLK2 256           // reduce-kernel block count

// ws layout (floats):
// [0, 6291456)      partials [512][3][4096]   (25.2 MB)
// [6291456, +256)   per-block v partials (K2)
// [6291712]         uint counter (K2 ticket; reset by K1 block 0)

__global__ __launch_bounds__(512) void fused_gram_kernel(
    const float* __restrict__ p1, const float* __restrict__ p2,
    float* __restrict__ partials, unsigned* __restrict__ cnt)
{
    __shared__ float la[16 * PAD];
    __shared__ float lb[16 * PAD];
    __shared__ float nred[32][17];
    __shared__ float sa[16], sb[16];
    const int t   = threadIdx.x;
    const int blk = blockIdx.x;
    const int b   = blk >> 6;          // batch 0..7
    const int oi  = (blk & 63) >> 1;   // input row strip 0..31
    const int h   = blk & 1;           // column half 0..1

    if (blk == 0 && t == 0) *cnt = 0u;   // reset K2's ticket each call

    // ---- pool 4x4 means: 64 ch x 16 oj x 2 inputs = 2048 slots, 4 iters.
    // m is uniform per iteration (k<2 -> p1, k>=2 -> p2).
    #pragma unroll
    for (int k = 0; k < 4; ++k) {
        const int idx  = k * 512 + t;         // 0..2047
        const int m    = idx >> 10;           // input select (uniform/iter)
        const int rest = idx & 1023;
        const int c    = rest >> 4;           // channel 0..63
        const int oj16 = rest & 15;           // row within block 0..15
        const long off = (long)((b * 64 + c) * 128 + oi * 4) * 128
                       + (h * 16 + oj16) * 4;
        const float* s = (m ? p2 : p1) + off;
        f4 v = *(const f4*)(s) + *(const f4*)(s + 128)
             + *(const f4*)(s + 256) + *(const f4*)(s + 384);
        float* dst = m ? lb : la;
        dst[oj16 * PAD + c] = ((v[0] + v[1]) + (v[2] + v[3])) * 0.0625f;
    }
    __syncthreads();

    // ---- row L2 norms: 2 inputs x 16 rows x 16 chunks of 4 ch = 512 thr
    {
        const int r = t & 15, g = t >> 4;     // g = 0..31
        const int m = g >> 4, q = g & 15;     // input, 4-ch chunk
        const float* src = m ? lb : la;
        float ss = 0.f;
        #pragma unroll
        for (int j = 0; j < 4; ++j) {
            const float v = src[r * PAD + q * 4 + j];
            ss = fmaf(v, v, ss);
        }
        nred[m * 16 + r][q] = ss;
    }
    __syncthreads();
    if (t < 32) {
        const int m = t >> 4, r = t & 15;
        float ss = 0.f;
        #pragma unroll
        for (int q = 0; q < 16; ++q) ss += nred[m * 16 + r][q];
        const float rs = 1.0f / fmaxf(sqrtf(ss), 1e-8f);
        if (m) sb[r] = rs; else sa[r] = rs;
    }
    __syncthreads();

    // ---- scale rows in place (m uniform per iteration)
    #pragma unroll
    for (int k = 0; k < 4; ++k) {
        const int idx  = k * 512 + t;
        const int m    = idx >> 10;
        const int rest = idx & 1023;
        const int r    = rest >> 6;           // row 0..15
        const int c    = rest & 63;           // channel (consecutive lanes)
        if (m) lb[r * PAD + c] *= sb[r];
        else   la[r * PAD + c] *= sa[r];
    }
    __syncthreads();

    // ---- three 64x64 channel Grams over this block's 16 rows.
    // thread owns 2x4 tile: gram rows c1,c1+1, cols c2..c2+3.
    const int c1 = (t >> 4) * 2;
    const int c2 = (t & 15) * 4;
    f4 aa0 = {}, aa1 = {}, ab0 = {}, ab1 = {}, bb0 = {}, bb1 = {};

    #pragma unroll 8
    for (int r = 0; r < 16; ++r) {
        const f2 a1 = *(const f2*)&la[r * PAD + c1];
        const f4 a2 = *(const f4*)&la[r * PAD + c2];
        const f2 b1 = *(const f2*)&lb[r * PAD + c1];
        const f4 b2 = *(const f4*)&lb[r * PAD + c2];
        aa0 += a2 * a1[0];  aa1 += a2 * a1[1];
        ab0 += b2 * a1[0];  ab1 += b2 * a1[1];
        bb0 += b2 * b1[0];  bb1 += b2 * b1[1];
    }

    float* P = partials + (long)blk * PART_STRIDE;
    *(f4*)&P[0 * 4096 + (c1    ) * 64 + c2] = aa0;
    *(f4*)&P[0 * 4096 + (c1 + 1) * 64 + c2] = aa1;
    *(f4*)&P[1 * 4096 + (c1    ) * 64 + c2] = ab0;
    *(f4*)&P[1 * 4096 + (c1 + 1) * 64 + c2] = ab1;
    *(f4*)&P[2 * 4096 + (c1    ) * 64 + c2] = bb0;
    *(f4*)&P[2 * 4096 + (c1 + 1) * 64 + c2] = bb1;
}

// K2: r3 structure; 256 blocks x 256 threads; each pc-chunk covers 32 partials.
__global__ __launch_bounds__(256) void reduce_kernel(
    const float* __restrict__ partials, float* __restrict__ bpart,
    unsigned* __restrict__ cnt, float* __restrict__ out)
{
    __shared__ float red[3][16][17];
    __shared__ float vred[16];
    __shared__ float fr[256];
    __shared__ unsigned last_flag;
    const int t  = threadIdx.x;
    const int el = t & 15;       // entry within block
    const int pc = t >> 4;       // partial chunk 0..15 (32 partials each)
    const int e  = blockIdx.x * 16 + el;

    float saa = 0.f, sab = 0.f, sbb = 0.f;
    #pragma unroll 4
    for (int i = 0; i < 32; ++i) {
        const float* P = partials + (long)(pc * 32 + i) * PART_STRIDE;
        saa += P[e];
        sab += P[4096 + e];
        sbb += P[8192 + e];
    }
    red[0][el][pc] = saa; red[1][el][pc] = sab; red[2][el][pc] = sbb;
    __syncthreads();

    if (t < 16) {
        float a = 0.f, m = 0.f, bv = 0.f;
        #pragma unroll
        for (int p = 0; p < 16; ++p) {
            a  += red[0][t][p];
            m  += red[1][t][p];
            bv += red[2][t][p];
        }
        vred[t] = fmaf(a, a, fmaf(bv, bv, -2.0f * (m * m)));
    }
    __syncthreads();

    if (t == 0) {
        float s = 0.f;
        #pragma unroll
        for (int i = 0; i < 16; ++i) s += vred[i];
        __hip_atomic_store(&bpart[blockIdx.x], s, __ATOMIC_RELEASE,
                           __HIP_MEMORY_SCOPE_AGENT);
        unsigned old = __hip_atomic_fetch_add(cnt, 1u, __ATOMIC_ACQ_REL,
                                              __HIP_MEMORY_SCOPE_AGENT);
        last_flag = (old == NBLK2 - 1) ? 1u : 0u;
    }
    __syncthreads();

    if (last_flag) {   // block-uniform
        fr[t] = __hip_atomic_load(&bpart[t], __ATOMIC_ACQUIRE,
                                  __HIP_MEMORY_SCOPE_AGENT);
        __syncthreads();
        for (int s2 = 128; s2 > 0; s2 >>= 1) {
            if (t < s2) fr[t] += fr[t + s2];
            __syncthreads();
        }
        if (t == 0) out[0] = fr[0] * (1.0f / 67108864.0f);  // / 8192^2
    }
}

extern "C" void kernel_launch(void* const* d_in, const int* in_sizes, int n_in,
                              void* d_out, int out_size, void* d_ws, size_t ws_size,
                              hipStream_t stream)
{
    const float* p1 = (const float*)d_in[0];
    const float* p2 = (const float*)d_in[1];
    float* ws       = (float*)d_ws;
    float* partials = ws;                                  // 512*12288
    float* bpart    = ws + (long)NPART * PART_STRIDE;      // 256
    unsigned* cnt   = (unsigned*)(bpart + NBLK2);          // 1

    fused_gram_kernel<<<NPART, 512, 0, stream>>>(p1, p2, partials, cnt);
    reduce_kernel   <<<NBLK2, 256, 0, stream>>>(partials, bpart, cnt, (float*)d_out);
}